// Round 3
// baseline (1260.292 us; speedup 1.0000x reference)
//
#include <hip/hip_runtime.h>
#include <hip/hip_bf16.h>
#include <math.h>
#include <stdint.h>

#define LRA 0.2f

typedef __attribute__((ext_vector_type(8))) short bf16x8;
typedef __attribute__((ext_vector_type(8))) unsigned short u16x8;
typedef __attribute__((ext_vector_type(4))) float f32x4;
typedef unsigned long long u64;

__device__ __forceinline__ unsigned short f2bf(float v) {
  union { float f; unsigned int u; } a; a.f = v;
  unsigned int u = a.u;
  return (unsigned short)((u + 0x7fffu + ((u >> 16) & 1u)) >> 16);
}
__device__ __forceinline__ float bf2f(unsigned short h) {
  union { float f; unsigned int u; } a; a.u = ((unsigned int)h) << 16;
  return a.f;
}
__device__ __forceinline__ float warp_max(float v){
  #pragma unroll
  for (int s = 32; s; s >>= 1) v = fmaxf(v, __shfl_xor(v, s));
  return v;
}
__device__ __forceinline__ float warp_sum(float v){
  #pragma unroll
  for (int s = 32; s; s >>= 1) v += __shfl_xor(v, s);
  return v;
}

// =============== adjacency -> bitmasks (once) ===============
__global__ __launch_bounds__(256) void k_mask(const int* __restrict__ adj, u64* __restrict__ mg){
  const int t = threadIdx.x, lane = t & 63, w = t >> 6, b = blockIdx.x;
  const int* adjb = adj + (size_t)b * 128 * 128;
  for (int i = w * 32; i < w * 32 + 32; ++i) {
    u64 b0 = __ballot(adjb[i * 128 + lane] > 0);
    u64 b1 = __ballot(adjb[i * 128 + 64 + lane] > 0);
    if (lane == 0) { mg[((size_t)b * 128 + i) * 2] = b0; mg[((size_t)b * 128 + i) * 2 + 1] = b1; }
  }
}

// =============== GEMM1: Wh = x @ W_heads[hd], transposed+packed out, s1/d1 ===============
__global__ __launch_bounds__(256) void k_gemm1(
    const float* __restrict__ x, const float* __restrict__ Whw,
    const float* __restrict__ asrc, const float* __restrict__ adst,
    unsigned int* __restrict__ buf1, float* __restrict__ s1g, float* __restrict__ d1g)
{
  __shared__ unsigned short Ah[128][40], Al[128][40], Bh[64][40], Bl[64][40];
  __shared__ float asl[64], adl[64];
  const int t = threadIdx.x, lane = t & 63, w = t >> 6, r = lane & 15, g = lane >> 4;
  const int bid = blockIdx.x;
  const int lb = ((bid & 7) << 9) | (bid >> 3);   // XCD chunk swizzle (4096 % 8 == 0)
  const int b = lb >> 3, hd = lb & 7;
  const size_t sl = (size_t)b * 8 + hd;
  const float* xb = x + (size_t)b * 128 * 133;
  const float* Bm = Whw + (size_t)hd * 133 * 60;
  unsigned int* slab = buf1 + sl * 7680;

  if (t < 64) {
    asl[t] = (t < 60) ? asrc[hd * 60 + t] : 0.f;
    adl[t] = (t < 60) ? adst[hd * 60 + t] : 0.f;
  }
  f32x4 acc[2][4];
  #pragma unroll
  for (int mt = 0; mt < 2; ++mt)
    #pragma unroll
    for (int nt = 0; nt < 4; ++nt) acc[mt][nt] = (f32x4){0.f,0.f,0.f,0.f};

  for (int kt = 0; kt < 133; kt += 32) {
    #pragma unroll
    for (int ii = 0; ii < 4; ++ii) {            // A: 128 rows x 32 k
      const int idx = t + ii * 256, ar = idx >> 3, aq = (idx & 7) * 4, gk = kt + aq;
      const float* ap = &xb[(size_t)ar * 133 + gk];
      float v0 = gk < 133 ? ap[0] : 0.f;
      float v1 = gk + 1 < 133 ? ap[1] : 0.f;
      float v2 = gk + 2 < 133 ? ap[2] : 0.f;
      float v3 = gk + 3 < 133 ? ap[3] : 0.f;
      unsigned short h0=f2bf(v0),h1=f2bf(v1),h2=f2bf(v2),h3=f2bf(v3);
      *(unsigned int*)&Ah[ar][aq]   = h0 | ((unsigned int)h1 << 16);
      *(unsigned int*)&Ah[ar][aq+2] = h2 | ((unsigned int)h3 << 16);
      unsigned short l0=f2bf(v0-bf2f(h0)),l1=f2bf(v1-bf2f(h1)),l2=f2bf(v2-bf2f(h2)),l3=f2bf(v3-bf2f(h3));
      *(unsigned int*)&Al[ar][aq]   = l0 | ((unsigned int)l1 << 16);
      *(unsigned int*)&Al[ar][aq+2] = l2 | ((unsigned int)l3 << 16);
    }
    #pragma unroll
    for (int ii = 0; ii < 4; ++ii) {            // B^T: 64 n x 32 k (pairs)
      const int idx = t + ii * 256, n = idx & 63, kk = (idx >> 6) * 2;
      float v0 = (n < 60 && kt + kk     < 133) ? Bm[(size_t)(kt + kk) * 60 + n] : 0.f;
      float v1 = (n < 60 && kt + kk + 1 < 133) ? Bm[(size_t)(kt + kk + 1) * 60 + n] : 0.f;
      unsigned short h0 = f2bf(v0), h1 = f2bf(v1);
      *(unsigned int*)&Bh[n][kk] = h0 | ((unsigned int)h1 << 16);
      unsigned short l0 = f2bf(v0 - bf2f(h0)), l1 = f2bf(v1 - bf2f(h1));
      *(unsigned int*)&Bl[n][kk] = l0 | ((unsigned int)l1 << 16);
    }
    __syncthreads();
    bf16x8 ah[2], al2[2];
    #pragma unroll
    for (int mt = 0; mt < 2; ++mt) {
      const int rr = w * 32 + mt * 16 + r;
      ah[mt]  = *(const bf16x8*)&Ah[rr][g * 8];
      al2[mt] = *(const bf16x8*)&Al[rr][g * 8];
    }
    #pragma unroll
    for (int nt = 0; nt < 4; ++nt) {
      const bf16x8 bh = *(const bf16x8*)&Bh[nt * 16 + r][g * 8];
      const bf16x8 bl = *(const bf16x8*)&Bl[nt * 16 + r][g * 8];
      #pragma unroll
      for (int mt = 0; mt < 2; ++mt) {
        acc[mt][nt] = __builtin_amdgcn_mfma_f32_16x16x32_bf16(ah[mt],  bh, acc[mt][nt], 0,0,0);
        acc[mt][nt] = __builtin_amdgcn_mfma_f32_16x16x32_bf16(al2[mt], bh, acc[mt][nt], 0,0,0);
        acc[mt][nt] = __builtin_amdgcn_mfma_f32_16x16x32_bf16(ah[mt],  bl, acc[mt][nt], 0,0,0);
      }
    }
    __syncthreads();
  }
  // store WhT packed + s/d epilogue
  #pragma unroll
  for (int mt = 0; mt < 2; ++mt) {
    #pragma unroll
    for (int nt = 0; nt < 4; ++nt) {
      const int cc = nt * 16 + r;
      if (cc < 60) {
        uint4 pv;
        unsigned int* pp = (unsigned int*)&pv;
        #pragma unroll
        for (int q = 0; q < 4; ++q) {
          float v = acc[mt][nt][q];
          unsigned short h = f2bf(v), l = f2bf(v - bf2f(h));
          pp[q] = ((unsigned int)h << 16) | l;
        }
        *(uint4*)&slab[(size_t)cc * 128 + w * 32 + mt * 16 + g * 4] = pv;
      }
    }
    float sv[4] = {0,0,0,0}, dv[4] = {0,0,0,0};
    #pragma unroll
    for (int nt = 0; nt < 4; ++nt) {
      const int cc = nt * 16 + r;
      const float as = asl[cc], ad = adl[cc];
      #pragma unroll
      for (int q = 0; q < 4; ++q) { sv[q] += acc[mt][nt][q] * as; dv[q] += acc[mt][nt][q] * ad; }
    }
    #pragma unroll
    for (int q = 0; q < 4; ++q) {
      #pragma unroll
      for (int s = 1; s <= 8; s <<= 1) { sv[q] += __shfl_xor(sv[q], s); dv[q] += __shfl_xor(dv[q], s); }
    }
    if (r == 0) {
      #pragma unroll
      for (int q = 0; q < 4; ++q) {
        s1g[sl * 128 + w * 32 + mt * 16 + g * 4 + q] = sv[q];
        d1g[sl * 128 + w * 32 + mt * 16 + g * 4 + q] = dv[q];
      }
    }
  }
}

// =============== att1: per (b,head); h = elu(att@Wh) in-place over WhT slice ===============
__global__ __launch_bounds__(256) void k_att1(
    unsigned int* __restrict__ buf1, const u64* __restrict__ mg,
    const float* __restrict__ s1g, const float* __restrict__ d1g)
{
  __shared__ unsigned short Th[16][64][8], Tl[16][64][8];   // fragment-major
  __shared__ float sarr[128], darr[128], marr[128], iarr[128];
  __shared__ u64 mAr[128], mBr[128];
  const int t = threadIdx.x, lane = t & 63, w = t >> 6, r = lane & 15, g = lane >> 4;
  const int bid = blockIdx.x;
  const int lb = ((bid & 7) << 9) | (bid >> 3);
  const int b = lb >> 3, hd = lb & 7;
  const size_t sl = (size_t)b * 8 + hd;
  unsigned int* slab = buf1 + sl * 7680;

  if (t < 128) {
    sarr[t] = s1g[sl * 128 + t];
    darr[t] = d1g[sl * 128 + t];
    mAr[t] = mg[((size_t)b * 128 + t) * 2];
    mBr[t] = mg[((size_t)b * 128 + t) * 2 + 1];
  }
  // stage packed WhT slice -> fragment-major hi/lo
  #pragma unroll
  for (int ii = 0; ii < 4; ++ii) {
    const int idx = t + ii * 256;
    const int c = idx & 63, jg = idx >> 6;       // c: lane-major for bank spread
    uint4 p0 = {0,0,0,0}, p1 = {0,0,0,0};
    if (c < 60) {
      const uint4* src = (const uint4*)&slab[(size_t)c * 128 + jg * 8];
      p0 = src[0]; p1 = src[1];
    }
    const unsigned int pw[8] = {p0.x,p0.y,p0.z,p0.w,p1.x,p1.y,p1.z,p1.w};
    u16x8 hv, lv;
    #pragma unroll
    for (int e = 0; e < 8; ++e) { hv[e] = (unsigned short)(pw[e] >> 16); lv[e] = (unsigned short)(pw[e] & 0xffffu); }
    const int tile = ((c >> 4) << 2) | (jg >> 2);
    const int li = ((jg & 3) << 4) | (c & 15);
    *(u16x8*)&Th[tile][li][0] = hv;
    *(u16x8*)&Tl[tile][li][0] = lv;
  }
  __syncthreads();
  // softmax stats (m, 1/sum) per row
  for (int i = w * 32; i < w * 32 + 32; ++i) {
    const u64 ma = mAr[i], mb2 = mBr[i];
    const float si = sarr[i];
    float e1 = -3e38f, e2 = -3e38f;
    if ((ma  >> lane) & 1ull) { float v = si + darr[lane];      e1 = v > 0.f ? v : LRA * v; }
    if ((mb2 >> lane) & 1ull) { float v = si + darr[64 + lane]; e2 = v > 0.f ? v : LRA * v; }
    const float m = warp_max(fmaxf(e1, e2));
    const float p1 = ((ma  >> lane) & 1ull) ? __expf(e1 - m) : 0.f;
    const float p2 = ((mb2 >> lane) & 1ull) ? __expf(e2 - m) : 0.f;
    const float sum = warp_sum(p1 + p2);
    if (lane == 0) { marr[i] = m; iarr[i] = 1.f / sum; }
  }
  __syncthreads();
  // attention A-fragments in registers
  bf16x8 pah[2][4], pal[2][4];
  #pragma unroll
  for (int mt = 0; mt < 2; ++mt) {
    const int i = w * 32 + mt * 16 + r;
    const float si = sarr[i], mi = marr[i], vi = iarr[i];
    const u64 ma = mAr[i], mb2 = mBr[i];
    #pragma unroll
    for (int kt = 0; kt < 4; ++kt) {
      #pragma unroll
      for (int e = 0; e < 8; ++e) {
        const int j = kt * 32 + g * 8 + e;
        const u64 mw = (kt < 2) ? ma : mb2;
        const int jb = j & 63;
        float v = si + darr[j];
        v = v > 0.f ? v : LRA * v;
        const float a = ((mw >> jb) & 1ull) ? __expf(v - mi) * vi : 0.f;
        const unsigned short h = f2bf(a);
        pah[mt][kt][e] = (short)h;
        pal[mt][kt][e] = (short)f2bf(a - bf2f(h));
      }
    }
  }
  // PV
  f32x4 acc[2][4];
  #pragma unroll
  for (int mt = 0; mt < 2; ++mt)
    #pragma unroll
    for (int nt = 0; nt < 4; ++nt) acc[mt][nt] = (f32x4){0.f,0.f,0.f,0.f};
  #pragma unroll
  for (int kt = 0; kt < 4; ++kt)
    #pragma unroll
    for (int nt = 0; nt < 4; ++nt) {
      const bf16x8 bh = *(const bf16x8*)&Th[(nt << 2) | kt][lane][0];
      const bf16x8 bl = *(const bf16x8*)&Tl[(nt << 2) | kt][lane][0];
      #pragma unroll
      for (int mt = 0; mt < 2; ++mt) {
        acc[mt][nt] = __builtin_amdgcn_mfma_f32_16x16x32_bf16(pah[mt][kt], bh, acc[mt][nt], 0,0,0);
        acc[mt][nt] = __builtin_amdgcn_mfma_f32_16x16x32_bf16(pal[mt][kt], bh, acc[mt][nt], 0,0,0);
        acc[mt][nt] = __builtin_amdgcn_mfma_f32_16x16x32_bf16(pah[mt][kt], bl, acc[mt][nt], 0,0,0);
      }
    }
  // ELU + packed in-place store (all global reads of slab completed pre-sync)
  #pragma unroll
  for (int mt = 0; mt < 2; ++mt)
    #pragma unroll
    for (int nt = 0; nt < 4; ++nt) {
      const int cc = nt * 16 + r;
      if (cc < 60) {
        #pragma unroll
        for (int q = 0; q < 4; ++q) {
          const int row = w * 32 + mt * 16 + g * 4 + q;
          float v = acc[mt][nt][q];
          v = v > 0.f ? v : __expf(v) - 1.f;
          const unsigned short h = f2bf(v), l = f2bf(v - bf2f(h));
          slab[(size_t)row * 60 + cc] = ((unsigned int)h << 16) | l;
        }
      }
    }
}

// =============== GEMM2: Wo = h @ W_out; WoT packed in-place; s2/d2 ===============
__global__ __launch_bounds__(512) void k_gemm2(
    unsigned int* __restrict__ buf1, const float* __restrict__ Wout,
    const float* __restrict__ aos, const float* __restrict__ aod,
    float* __restrict__ s2g, float* __restrict__ d2g)
{
  __shared__ unsigned short Ah[128][40], Al[128][40], Bh[320][40], Bl[320][40];
  __shared__ float aosl[320], aodl[320];
  const int t = threadIdx.x, lane = t & 63, w = t >> 6, r = lane & 15, g = lane >> 4;
  const int b = blockIdx.x;
  unsigned int* slab = buf1 + (size_t)b * 61440;
  if (t < 320) { aosl[t] = t < 300 ? aos[t] : 0.f; aodl[t] = t < 300 ? aod[t] : 0.f; }

  f32x4 acc[20];
  #pragma unroll
  for (int nt = 0; nt < 20; ++nt) acc[nt] = (f32x4){0.f,0.f,0.f,0.f};

  for (int kt = 0; kt < 480; kt += 32) {
    #pragma unroll
    for (int ii = 0; ii < 4; ++ii) {            // A: 128 rows x 32 k (packed u32, k->(hd,c))
      const int idx = t + ii * 512, ar = idx >> 4, kp = (idx & 15) * 2;
      const int k0 = kt + kp, k1 = k0 + 1;
      const int h0 = k0 / 60, c0 = k0 - h0 * 60;
      const int h1 = k1 / 60, c1 = k1 - h1 * 60;
      const unsigned int p0 = slab[((size_t)h0 * 128 + ar) * 60 + c0];
      const unsigned int p1 = slab[((size_t)h1 * 128 + ar) * 60 + c1];
      *(unsigned int*)&Ah[ar][kp] = (p0 >> 16) | (p1 & 0xffff0000u);
      *(unsigned int*)&Al[ar][kp] = (p0 & 0xffffu) | (p1 << 16);
    }
    #pragma unroll
    for (int ii = 0; ii < 20; ++ii) {           // B^T: 320 n x 32 k
      const int idx = t + ii * 512;
      const int n = idx % 320, kk = idx / 320;
      const float v = (n < 300) ? Wout[(size_t)(kt + kk) * 300 + n] : 0.f;
      const unsigned short h = f2bf(v);
      Bh[n][kk] = h; Bl[n][kk] = f2bf(v - bf2f(h));
    }
    __syncthreads();
    const bf16x8 ah  = *(const bf16x8*)&Ah[w * 16 + r][g * 8];
    const bf16x8 al2 = *(const bf16x8*)&Al[w * 16 + r][g * 8];
    #pragma unroll
    for (int nt = 0; nt < 20; ++nt) {
      const bf16x8 bh = *(const bf16x8*)&Bh[nt * 16 + r][g * 8];
      const bf16x8 bl = *(const bf16x8*)&Bl[nt * 16 + r][g * 8];
      acc[nt] = __builtin_amdgcn_mfma_f32_16x16x32_bf16(ah,  bh, acc[nt], 0,0,0);
      acc[nt] = __builtin_amdgcn_mfma_f32_16x16x32_bf16(al2, bh, acc[nt], 0,0,0);
      acc[nt] = __builtin_amdgcn_mfma_f32_16x16x32_bf16(ah,  bl, acc[nt], 0,0,0);
    }
    __syncthreads();
  }
  // WoT packed in-place + s2/d2
  #pragma unroll
  for (int nt = 0; nt < 20; ++nt) {
    const int cc = nt * 16 + r;
    if (cc < 300) {
      uint4 pv;
      unsigned int* pp = (unsigned int*)&pv;
      #pragma unroll
      for (int q = 0; q < 4; ++q) {
        const float v = acc[nt][q];
        const unsigned short h = f2bf(v), l = f2bf(v - bf2f(h));
        pp[q] = ((unsigned int)h << 16) | l;
      }
      *(uint4*)&slab[(size_t)cc * 128 + w * 16 + g * 4] = pv;
    }
  }
  float sv[4] = {0,0,0,0}, dv[4] = {0,0,0,0};
  #pragma unroll
  for (int nt = 0; nt < 20; ++nt) {
    const int cc = nt * 16 + r;
    const float as = aosl[cc], ad = aodl[cc];
    #pragma unroll
    for (int q = 0; q < 4; ++q) { sv[q] += acc[nt][q] * as; dv[q] += acc[nt][q] * ad; }
  }
  #pragma unroll
  for (int q = 0; q < 4; ++q) {
    #pragma unroll
    for (int s = 1; s <= 8; s <<= 1) { sv[q] += __shfl_xor(sv[q], s); dv[q] += __shfl_xor(dv[q], s); }
  }
  if (r == 0) {
    #pragma unroll
    for (int q = 0; q < 4; ++q) {
      s2g[(size_t)b * 128 + w * 16 + g * 4 + q] = sv[q];
      d2g[(size_t)b * 128 + w * 16 + g * 4 + q] = dv[q];
    }
  }
}

// =============== att2 + elu + log_softmax(features) + mean (rank-1) ===============
__global__ __launch_bounds__(256) void k_att2(
    const unsigned int* __restrict__ buf1, const u64* __restrict__ mg,
    const float* __restrict__ s2g, const float* __restrict__ d2g,
    float* __restrict__ gat)
{
  __shared__ unsigned short Th[16][64][8], Tl[16][64][8];
  __shared__ float sarr[128], darr[128], marr[128], iarr[128];
  __shared__ u64 mAr[128], mBr[128];
  __shared__ float colsum[304];
  __shared__ float srow[16];
  const int t = threadIdx.x, lane = t & 63, w = t >> 6, r = lane & 15, g = lane >> 4;
  const int b = blockIdx.x;
  const unsigned int* slab = buf1 + (size_t)b * 61440;

  if (t < 128) {
    sarr[t] = s2g[(size_t)b * 128 + t];
    darr[t] = d2g[(size_t)b * 128 + t];
    mAr[t] = mg[((size_t)b * 128 + t) * 2];
    mBr[t] = mg[((size_t)b * 128 + t) * 2 + 1];
  }
  for (int c = t; c < 304; c += 256) colsum[c] = 0.f;
  __syncthreads();
  for (int i = w * 32; i < w * 32 + 32; ++i) {
    const u64 ma = mAr[i], mb2 = mBr[i];
    const float si = sarr[i];
    float e1 = -3e38f, e2 = -3e38f;
    if ((ma  >> lane) & 1ull) { float v = si + darr[lane];      e1 = v > 0.f ? v : LRA * v; }
    if ((mb2 >> lane) & 1ull) { float v = si + darr[64 + lane]; e2 = v > 0.f ? v : LRA * v; }
    const float m = warp_max(fmaxf(e1, e2));
    const float p1 = ((ma  >> lane) & 1ull) ? __expf(e1 - m) : 0.f;
    const float p2 = ((mb2 >> lane) & 1ull) ? __expf(e2 - m) : 0.f;
    const float sum = warp_sum(p1 + p2);
    if (lane == 0) { marr[i] = m; iarr[i] = 1.f / sum; }
  }
  __syncthreads();
  bf16x8 pah[2][4], pal[2][4];
  #pragma unroll
  for (int mt = 0; mt < 2; ++mt) {
    const int i = w * 32 + mt * 16 + r;
    const float si = sarr[i], mi = marr[i], vi = iarr[i];
    const u64 ma = mAr[i], mb2 = mBr[i];
    #pragma unroll
    for (int kt = 0; kt < 4; ++kt) {
      #pragma unroll
      for (int e = 0; e < 8; ++e) {
        const int j = kt * 32 + g * 8 + e;
        const u64 mw = (kt < 2) ? ma : mb2;
        const int jb = j & 63;
        float v = si + darr[j];
        v = v > 0.f ? v : LRA * v;
        const float a = ((mw >> jb) & 1ull) ? __expf(v - mi) * vi : 0.f;
        const unsigned short h = f2bf(a);
        pah[mt][kt][e] = (short)h;
        pal[mt][kt][e] = (short)f2bf(a - bf2f(h));
      }
    }
  }
  float m8[2][4], l8[2][4];
  #pragma unroll
  for (int mt = 0; mt < 2; ++mt)
    #pragma unroll
    for (int q = 0; q < 4; ++q) { m8[mt][q] = -3e38f; l8[mt][q] = 0.f; }

  for (int ch = 0; ch < 5; ++ch) {
    #pragma unroll
    for (int ii = 0; ii < 4; ++ii) {
      const int idx = t + ii * 256;
      const int c = idx & 63, jg = idx >> 6;
      const int gc = ch * 64 + c;
      uint4 p0 = {0,0,0,0}, p1 = {0,0,0,0};
      if (gc < 300) {
        const uint4* src = (const uint4*)&slab[(size_t)gc * 128 + jg * 8];
        p0 = src[0]; p1 = src[1];
      }
      const unsigned int pw[8] = {p0.x,p0.y,p0.z,p0.w,p1.x,p1.y,p1.z,p1.w};
      u16x8 hv, lv;
      #pragma unroll
      for (int e = 0; e < 8; ++e) { hv[e] = (unsigned short)(pw[e] >> 16); lv[e] = (unsigned short)(pw[e] & 0xffffu); }
      const int tile = ((c >> 4) << 2) | (jg >> 2);
      const int li = ((jg & 3) << 4) | (c & 15);
      *(u16x8*)&Th[tile][li][0] = hv;
      *(u16x8*)&Tl[tile][li][0] = lv;
    }
    __syncthreads();
    f32x4 pacc[2][4];
    #pragma unroll
    for (int mt = 0; mt < 2; ++mt)
      #pragma unroll
      for (int nt = 0; nt < 4; ++nt) pacc[mt][nt] = (f32x4){0.f,0.f,0.f,0.f};
    #pragma unroll
    for (int kt = 0; kt < 4; ++kt)
      #pragma unroll
      for (int nt = 0; nt < 4; ++nt) {
        const bf16x8 bh = *(const bf16x8*)&Th[(nt << 2) | kt][lane][0];
        const bf16x8 bl = *(const bf16x8*)&Tl[(nt << 2) | kt][lane][0];
        #pragma unroll
        for (int mt = 0; mt < 2; ++mt) {
          pacc[mt][nt] = __builtin_amdgcn_mfma_f32_16x16x32_bf16(pah[mt][kt], bh, pacc[mt][nt], 0,0,0);
          pacc[mt][nt] = __builtin_amdgcn_mfma_f32_16x16x32_bf16(pal[mt][kt], bh, pacc[mt][nt], 0,0,0);
          pacc[mt][nt] = __builtin_amdgcn_mfma_f32_16x16x32_bf16(pah[mt][kt], bl, pacc[mt][nt], 0,0,0);
        }
      }
    float csA[4] = {0,0,0,0};
    #pragma unroll
    for (int mt = 0; mt < 2; ++mt) {
      float vq[4][4];
      #pragma unroll
      for (int nt = 0; nt < 4; ++nt) {
        const int cc = ch * 64 + nt * 16 + r;
        const bool cv = cc < 300;
        #pragma unroll
        for (int q = 0; q < 4; ++q) {
          float v = pacc[mt][nt][q];
          v = v > 0.f ? v : __expf(v) - 1.f;
          vq[nt][q] = cv ? v : -3e38f;
          csA[nt] += cv ? v : 0.f;
        }
      }
      #pragma unroll
      for (int q = 0; q < 4; ++q) {
        float mx = fmaxf(fmaxf(vq[0][q], vq[1][q]), fmaxf(vq[2][q], vq[3][q]));
        mx = fmaxf(mx, __shfl_xor(mx, 1));
        mx = fmaxf(mx, __shfl_xor(mx, 2));
        mx = fmaxf(mx, __shfl_xor(mx, 4));
        mx = fmaxf(mx, __shfl_xor(mx, 8));
        const float nm = fmaxf(m8[mt][q], mx);
        float ps = __expf(vq[0][q]-nm) + __expf(vq[1][q]-nm) + __expf(vq[2][q]-nm) + __expf(vq[3][q]-nm);
        ps += __shfl_xor(ps, 1); ps += __shfl_xor(ps, 2);
        ps += __shfl_xor(ps, 4); ps += __shfl_xor(ps, 8);
        l8[mt][q] = l8[mt][q] * __expf(m8[mt][q] - nm) + ps;
        m8[mt][q] = nm;
      }
    }
    #pragma unroll
    for (int nt = 0; nt < 4; ++nt) {
      float cs = csA[nt];
      cs += __shfl_xor(cs, 16); cs += __shfl_xor(cs, 32);
      const int cc = ch * 64 + nt * 16 + r;
      if (g == 0 && cc < 300) atomicAdd(&colsum[cc], cs);
    }
    __syncthreads();
  }
  if (r == 0) {
    float sp = 0.f;
    #pragma unroll
    for (int mt = 0; mt < 2; ++mt)
      #pragma unroll
      for (int q = 0; q < 4; ++q) sp += m8[mt][q] + __logf(l8[mt][q]);
    srow[w * 4 + g] = sp;
  }
  __syncthreads();
  float S = 0.f;
  #pragma unroll
  for (int k = 0; k < 16; ++k) S += srow[k];
  for (int c = t; c < 300; c += 256)
    gat[(size_t)b * 300 + c] = (colsum[c] - S) * (1.f / 128.f);
}

// =============== FPN (4 batches/block) ===============
__global__ __launch_bounds__(256) void k_fpn(
    const float* __restrict__ fp, const float* __restrict__ w1, const float* __restrict__ b1,
    const float* __restrict__ w2, const float* __restrict__ b2, float* __restrict__ fpn)
{
  __shared__ float fpl[4][1492];
  __shared__ float f1[4][516];
  const int t = threadIdx.x, bb = blockIdx.x * 4;
  #pragma unroll
  for (int rr = 0; rr < 4; ++rr)
    for (int k = t; k < 1489; k += 256)
      fpl[rr][k] = fp[(size_t)(bb + rr) * 1489 + k];
  __syncthreads();
  for (int c = t; c < 512; c += 256) {
    float a0 = b1[c], a1 = a0, a2 = a0, a3 = a0;
    a0 = b1[c]; a1 = a0; a2 = a0; a3 = a0;
    #pragma unroll 4
    for (int k = 0; k < 1489; ++k) {
      const float wv = w1[(size_t)k * 512 + c];
      a0 += fpl[0][k] * wv; a1 += fpl[1][k] * wv;
      a2 += fpl[2][k] * wv; a3 += fpl[3][k] * wv;
    }
    f1[0][c] = fmaxf(a0, 0.f); f1[1][c] = fmaxf(a1, 0.f);
    f1[2][c] = fmaxf(a2, 0.f); f1[3][c] = fmaxf(a3, 0.f);
  }
  __syncthreads();
  for (int c = t; c < 300; c += 256) {
    float a0 = b2[c], a1 = a0, a2 = a0, a3 = a0;
    #pragma unroll 4
    for (int k = 0; k < 512; ++k) {
      const float wv = w2[(size_t)k * 300 + c];
      a0 += f1[0][k] * wv; a1 += f1[1][k] * wv;
      a2 += f1[2][k] * wv; a3 += f1[3][k] * wv;
    }
    fpn[(size_t)(bb + 0) * 300 + c] = a0;
    fpn[(size_t)(bb + 1) * 300 + c] = a1;
    fpn[(size_t)(bb + 2) * 300 + c] = a2;
    fpn[(size_t)(bb + 3) * 300 + c] = a3;
  }
}

// =============== fusion head (4 batches/block) ===============
__global__ __launch_bounds__(256) void k_head(
    const float* __restrict__ gat, const float* __restrict__ fpn,
    const float* __restrict__ gw, const float* __restrict__ gb,
    const float* __restrict__ fw, const float* __restrict__ fb,
    const float* __restrict__ w1, const float* __restrict__ b1,
    const float* __restrict__ w2, const float* __restrict__ b2,
    float* __restrict__ out)
{
  __shared__ float grl[4][300], frl[4][300], zl[4][600], z1l[4][304];
  const int t = threadIdx.x, lane = t & 63, w = t >> 6, bb = blockIdx.x * 4;
  #pragma unroll
  for (int rr = 0; rr < 4; ++rr)
    for (int k = t; k < 300; k += 256) {
      grl[rr][k] = gat[(size_t)(bb + rr) * 300 + k];
      frl[rr][k] = fpn[(size_t)(bb + rr) * 300 + k];
    }
  __syncthreads();
  for (int c = t; c < 300; c += 256) {
    float ag0 = gb[c], ag1 = ag0, ag2 = ag0, ag3 = ag0;
    float af0 = fb[c], af1 = af0, af2 = af0, af3 = af0;
    #pragma unroll 2
    for (int k = 0; k < 300; ++k) {
      const float gv = gw[(size_t)k * 300 + c];
      const float fv = fw[(size_t)k * 300 + c];
      ag0 += grl[0][k] * gv; ag1 += grl[1][k] * gv; ag2 += grl[2][k] * gv; ag3 += grl[3][k] * gv;
      af0 += frl[0][k] * fv; af1 += frl[1][k] * fv; af2 += frl[2][k] * fv; af3 += frl[3][k] * fv;
    }
    zl[0][c] = fmaxf(ag0, 0.f); zl[1][c] = fmaxf(ag1, 0.f);
    zl[2][c] = fmaxf(ag2, 0.f); zl[3][c] = fmaxf(ag3, 0.f);
    zl[0][300 + c] = fmaxf(af0, 0.f); zl[1][300 + c] = fmaxf(af1, 0.f);
    zl[2][300 + c] = fmaxf(af2, 0.f); zl[3][300 + c] = fmaxf(af3, 0.f);
  }
  __syncthreads();
  for (int c = t; c < 300; c += 256) {
    float a0 = b1[c], a1 = a0, a2 = a0, a3 = a0;
    #pragma unroll 2
    for (int k = 0; k < 600; ++k) {
      const float wv = w1[(size_t)k * 300 + c];
      a0 += zl[0][k] * wv; a1 += zl[1][k] * wv; a2 += zl[2][k] * wv; a3 += zl[3][k] * wv;
    }
    z1l[0][c] = fmaxf(a0, 0.f); z1l[1][c] = fmaxf(a1, 0.f);
    z1l[2][c] = fmaxf(a2, 0.f); z1l[3][c] = fmaxf(a3, 0.f);
  }
  __syncthreads();
  float p = 0.f;
  for (int k = lane; k < 300; k += 64) p += z1l[w][k] * w2[k];
  p = warp_sum(p);
  if (lane == 0) {
    const float z = p + b2[0];
    out[bb + w] = 1.f / (1.f + __expf(-z));
  }
}

extern "C" void kernel_launch(void* const* d_in, const int* in_sizes, int n_in,
                              void* d_out, int out_size, void* d_ws, size_t ws_size,
                              hipStream_t stream)
{
  const float* x    = (const float*)d_in[0];
  const int*   adj  = (const int*)d_in[1];
  const float* fp   = (const float*)d_in[2];
  const float* Whw  = (const float*)d_in[3];
  const float* asrc = (const float*)d_in[4];
  const float* adst = (const float*)d_in[5];
  const float* Wout = (const float*)d_in[6];
  const float* aos  = (const float*)d_in[7];
  const float* aod  = (const float*)d_in[8];
  const float* fc1w = (const float*)d_in[9];
  const float* fc1b = (const float*)d_in[10];
  const float* fc2w = (const float*)d_in[11];
  const float* fc2b = (const float*)d_in[12];
  const float* fcgw = (const float*)d_in[13];
  const float* fcgb = (const float*)d_in[14];
  const float* fcfw = (const float*)d_in[15];
  const float* fcfb = (const float*)d_in[16];
  const float* f1w  = (const float*)d_in[17];
  const float* f1b  = (const float*)d_in[18];
  const float* f2w  = (const float*)d_in[19];
  const float* f2b  = (const float*)d_in[20];
  float* out = (float*)d_out;

  char* wsb = (char*)d_ws;
  unsigned int* buf1 = (unsigned int*)wsb;                       // 125,829,120 B
  float* s1g = (float*)(wsb + 125829120);                        // 2 MB
  float* d1g = (float*)(wsb + 127926272);                        // 2 MB
  float* s2g = (float*)(wsb + 130023424);                        // 256 KB
  float* d2g = (float*)(wsb + 130285568);                        // 256 KB
  u64*   mgb = (u64*)  (wsb + 130547712);                        // 1 MB
  float* gatp = (float*)(wsb + 131596288);                       // 600 KB
  float* fpnp = (float*)(wsb + 132210688);                       // 600 KB

  k_mask <<<512, 256, 0, stream>>>(adj, mgb);
  k_gemm1<<<4096, 256, 0, stream>>>(x, Whw, asrc, adst, buf1, s1g, d1g);
  k_att1 <<<4096, 256, 0, stream>>>(buf1, mgb, s1g, d1g);
  k_gemm2<<<512, 512, 0, stream>>>(buf1, Wout, aos, aod, s2g, d2g);
  k_att2 <<<512, 256, 0, stream>>>(buf1, mgb, s2g, d2g, gatp);
  k_fpn  <<<128, 256, 0, stream>>>(fp, fc1w, fc1b, fc2w, fc2b, fpnp);
  k_head <<<128, 256, 0, stream>>>(gatp, fpnp, fcgw, fcgb, fcfw, fcfb,
                                   f1w, f1b, f2w, f2b, out);
}